// Round 13
// baseline (20.577 us; speedup 1.0000x reference)
//
#include <hip/hip_runtime.h>
#include <stdint.h>
#include <math.h>

// SamplePatches: gumbel top-k sampling (Threefry2x32 counter-mode, key 42) + patch gather.
// Inputs: d_in[0]=x_low (unused), d_in[1]=x_high (unused),
//         d_in[2]=attention [4,64,64] f32, d_in[3]=WSI [4,3,2048,2048] f32.
// Output: patches [4,32,3,128,128] f32 then sampled_attention [4,32] f32, concat flat.
//
// JAX defaults jax_threefry_partitionable=True: bits for element e are
// threefry2x32(key, (hi=0, lo=e)) with the two output words XOR-folded.
//
// SINGLE plain kernel, batch-specialized redundancy (64 blocks/batch).
// Selection via EXACT histogram select:
//   - fast __logf scores -> monotone u32 keys -> 8192-bin LDS histogram stored
//     TRANSPOSED+PADDED (addr = (f&63)*129 + (f>>6)) so the coarse reduction
//     and fine suffix scan are bank-conflict-free
//   - one-wave suffix scan finds fine bin t* of the 32nd-largest fast key
//   - candidates = all elements in bins >= t*-2 (margin >> fast-vs-exact error)
//   - candidates re-scored inline with the EXACT ocml logf formula
//     (bit-identical to all prior passing rounds), ranked by
//     (value desc, j asc) == lax.top_k.

namespace {
constexpr int B      = 4;
constexpr int NP     = 32;     // N_PATCHES
constexpr int PATCH_ = 128;
constexpr int GRID   = 4096;   // 64*64 attention cells per batch
constexpr int HW     = 2048;
constexpr int NT     = 1024;   // threads per block
constexpr int BPB    = 64;     // blocks per batch
constexpr int NBLK   = B * BPB;          // 256 blocks, one per CU
constexpr int NW     = NT / 64;          // 16 waves
constexpr int QP     = GRID / NT;        // 4 scores per thread
constexpr int FSTR   = 129;    // padded stride for transposed histogram
constexpr int HWORDS = 64 * FSTR;        // 8256 words (~33 KB)
constexpr int NCB    = 128;    // coarse bins: 64 fine each
constexpr int MAXC   = 512;    // candidate capacity (expected ~40-90)
constexpr int GITER  = 6;      // gather float4s per thread
constexpr float EPSF = 1e-12f;

typedef float f32x4 __attribute__((ext_vector_type(4)));

__device__ inline uint32_t rotl32(uint32_t x, uint32_t r){ return (x<<r)|(x>>(32u-r)); }

// Threefry-2x32 with key (0, 42)  == jax.random.key(42)
__device__ inline void threefry2x32_k042(uint32_t x0, uint32_t x1,
                                         uint32_t& o0, uint32_t& o1){
  const uint32_t k0 = 0u, k1 = 42u;
  const uint32_t k2 = k0 ^ k1 ^ 0x1BD11BDAu;
  x0 += k0; x1 += k1;
#define RND(r) { x0 += x1; x1 = rotl32(x1,(r)); x1 ^= x0; }
#define G_A RND(13) RND(15) RND(26) RND(6)
#define G_B RND(17) RND(29) RND(16) RND(24)
  G_A x0 += k1; x1 += k2 + 1u;
  G_B x0 += k2; x1 += k0 + 2u;
  G_A x0 += k0; x1 += k1 + 3u;
  G_B x0 += k1; x1 += k2 + 4u;
  G_A x0 += k2; x1 += k0 + 5u;
#undef G_A
#undef G_B
#undef RND
  o0 = x0; o1 = x1;
}

// Monotone map: u32 compare order == f32 value order.
__device__ inline uint32_t mono_f32(float v){
  const uint32_t bits = __float_as_uint(v);
  return (bits & 0x80000000u) ? ~bits : (bits | 0x80000000u);
}

// transposed+padded histogram address for logical fine bin f
__device__ inline int haddr(int f){ return (f & 63) * FSTR + (f >> 6); }

// uniform bits -> [0,1) float, identical to jax (bits>>9 | one) - 1
__device__ inline float u01(uint32_t bits){
  return __uint_as_float((bits >> 9) | 0x3F800000u) - 1.0f;
}

__global__ __launch_bounds__(NT) void fused_sample_gather(
    const float* __restrict__ att, const float* __restrict__ wsi,
    float* __restrict__ out_attn, f32x4* __restrict__ out4){
  const int tid  = threadIdx.x;
  const int wv   = tid >> 6;        // wave id 0..15
  const int lane = tid & 63;
  const int b    = blockIdx.x >> 6; // this block's batch
  const int g    = blockIdx.x & 63; // slice index within batch
  __shared__ uint32_t hist[HWORDS]; // transposed+padded, ~33 KB
  __shared__ uint32_t coarse[NCB];
  __shared__ float redv[NW];
  __shared__ int   scnt;
  __shared__ int   stcut;
  __shared__ unsigned long long dkey[MAXC];
  __shared__ float dprob[MAXC];
  __shared__ int2  gtab[NP];        // n -> (y0, x0), this batch only

  const float* a = att + b * GRID;

  // one float4 per thread: j = tid*4 + q (contiguous)
  const float4 va = reinterpret_cast<const float4*>(a)[tid];
  float areg[QP] = {va.x, va.y, va.z, va.w};

  // zero histogram + counter (completes before the barrier below)
  for (int i = tid; i < HWORDS; i += NT) hist[i] = 0u;
  if (tid == 0) scnt = 0;

  // ---- sum(attention row): wave partials, then every thread accumulates
  //      redv[0..15] in the same order (bit-identical to prior rounds) ----
  float local = areg[0] + areg[1] + areg[2] + areg[3];
  #pragma unroll
  for (int d = 1; d < 64; d <<= 1) local += __shfl_xor(local, d, 64);
  if (lane == 0) redv[wv] = local;
  __syncthreads();                                   // B1
  float sum = 0.f;
  #pragma unroll
  for (int w = 0; w < NW; ++w) sum += redv[w];       // broadcast reads

  // ---- fast scores (filter only) -> monotone keys -> histogram ----
  uint32_t kreg[QP];
  #pragma unroll
  for (int q = 0; q < QP; ++q){
    const int e = b * GRID + (tid << 2) + q;         // flat element in [0, 16384)
    uint32_t o0, o1;
    threefry2x32_k042(0u, (uint32_t)e, o0, o1);
    const float u = u01(o0 ^ o1);
    const float gum = -__logf(-__logf(u + EPSF) + EPSF);   // fast v_log path
    const float s   = __logf(areg[q] / sum + EPSF) + gum;
    kreg[q] = mono_f32(s);
    atomicAdd(&hist[haddr((int)(kreg[q] >> 19))], 1u);
  }
  __syncthreads();                                   // B2

  // ---- coarse histogram: conflict-free (lanes read consecutive addresses) ----
  if (tid < NCB){
    uint32_t s = 0;
    #pragma unroll
    for (int i = 0; i < 64; ++i) s += hist[i * FSTR + tid];
    coarse[tid] = s;
  }
  __syncthreads();                                   // B3

  // ---- one-wave suffix scan: find fine bin t* of the 32nd-largest key ----
  if (wv == 0){
    uint32_t vlo = coarse[lane], vhi = coarse[lane + 64];
    #pragma unroll
    for (int d = 1; d < 64; d <<= 1){
      uint32_t t = __shfl_down(vhi, d, 64); if (lane + d < 64) vhi += t;
      t = __shfl_down(vlo, d, 64);          if (lane + d < 64) vlo += t;
    }
    const uint32_t Thi = __shfl(vhi, 0, 64);   // total of hi half
    const uint32_t Slo = vlo + Thi;            // S(c = lane)
    const unsigned long long mhi = __ballot(vhi >= (uint32_t)NP);
    const unsigned long long mlo = __ballot(Slo >= (uint32_t)NP);
    const int cstar = mhi ? (64 + (63 - __clzll(mhi))) : (63 - __clzll(mlo));
    // A = S(cstar+1): count strictly above coarse bin cstar
    const int cn = cstar + 1;
    const uint32_t t1 = __shfl(vhi, (cn - 64) & 63, 64);
    const uint32_t t2 = __shfl(Slo, cn & 63, 64);
    const uint32_t A  = (cn >= 128) ? 0u : ((cn >= 64) ? t1 : t2);
    // fine suffix within coarse bin cstar (distinct banks: 129 % 32 == 1)
    uint32_t f = hist[lane * FSTR + cstar];
    #pragma unroll
    for (int d = 1; d < 64; d <<= 1){
      uint32_t t = __shfl_down(f, d, 64); if (lane + d < 64) f += t;
    }
    const unsigned long long mf = __ballot(A + f >= (uint32_t)NP);
    const int lstar = 63 - __clzll(mf);        // exists: C(cstar*64) >= 32
    if (lane == 0) stcut = cstar * 64 + lstar - 2;   // 2-bin safety margin
  }
  __syncthreads();                                   // B4
  const int tcut = stcut;

  // ---- append candidates + EXACT inline re-score (bit-identical ocml logf) ----
  #pragma unroll
  for (int q = 0; q < QP; ++q){
    if ((int)(kreg[q] >> 19) >= tcut){
      const int p = atomicAdd(&scnt, 1);
      if (p < MAXC){
        const int j = (tid << 2) + q;
        uint32_t o0, o1;
        threefry2x32_k042(0u, (uint32_t)(b * GRID + j), o0, o1);
        const float u = u01(o0 ^ o1);
        const float gum  = -logf(-logf(u + EPSF) + EPSF);
        const float prob = areg[q] / sum;
        const float se   = logf(prob + EPSF) + gum;
        dkey[p]  = ((unsigned long long)mono_f32(se) << 32)
                 | (uint32_t)(GRID - 1 - j);
        dprob[p] = prob;
      }
    }
  }
  __syncthreads();                                   // B5
  const int M = scnt < MAXC ? scnt : MAXC;

  // ---- exact rank among M candidates (broadcast reads); rank < 32 -> emit ----
  if (tid < M){
    const unsigned long long mk = dkey[tid];
    int rank = 0;
    #pragma unroll 4
    for (int c = 0; c < M; ++c) rank += (dkey[c] > mk) ? 1 : 0;
    if (rank < NP){
      const int j   = GRID - 1 - (int)(uint32_t)(mk & 0xFFFFFFFFull);
      const int row = j >> 6, col = j & 63;
      int y0 = row * 32 - 48; y0 = y0 < 0 ? 0 : (y0 > 1920 ? 1920 : y0);
      int x0 = col * 32 - 48; x0 = x0 < 0 ? 0 : (x0 > 1920 ? 1920 : x0);
      gtab[rank] = make_int2(y0, x0);
      if (g == 0) out_attn[b * NP + rank] = dprob[tid];
    }
  }
  __syncthreads();                                   // B6

  // ================= gather: this block's 1/64 slice of its batch ============
  // per batch: rows = 32*3*128 = 12288, each row = 32 float4.
  int t = g * NT + tid;                       // [0, 65536) per iteration step
  #pragma unroll
  for (int it = 0; it < GITER; ++it, t += BPB * NT){
    const int l4   = t & 31;          // float4 within the 128-float row
    const int rowb = t >> 5;          // [0, 12288) within batch
    const int r    = rowb & 127;
    const int tmp  = rowb >> 7;       // n*3 + c, [0, 96)
    const int c    = tmp % 3;
    const int n    = tmp / 3;
    const int2 yx  = gtab[n];         // (y0, x0); x0 multiple of 16 -> aligned
    const size_t off = ((size_t)((b * 3 + c) * HW + yx.x + r)) * HW + (size_t)yx.y;
    const f32x4 v = *reinterpret_cast<const f32x4*>(wsi + off + (size_t)l4 * 4);
    __builtin_nontemporal_store(v, out4 + ((size_t)b * 12288 + rowb) * 32 + l4);
  }
}
} // namespace

extern "C" void kernel_launch(void* const* d_in, const int* in_sizes, int n_in,
                              void* d_out, int out_size, void* d_ws, size_t ws_size,
                              hipStream_t stream) {
  const float* att = (const float*)d_in[2];
  const float* wsi = (const float*)d_in[3];
  float* out       = (float*)d_out;
  float* out_attn  = out + (size_t)B * NP * 3 * PATCH_ * PATCH_;  // 6,291,456

  fused_sample_gather<<<NBLK, NT, 0, stream>>>(att, wsi, out_attn, (f32x4*)out);
}

// Round 14
// 19.417 us; speedup vs baseline: 1.0597x; 1.0597x over previous
//
#include <hip/hip_runtime.h>
#include <stdint.h>
#include <math.h>

// SamplePatches: gumbel top-k sampling (Threefry2x32 counter-mode, key 42) + patch gather.
// Inputs: d_in[0]=x_low (unused), d_in[1]=x_high (unused),
//         d_in[2]=attention [4,64,64] f32, d_in[3]=WSI [4,3,2048,2048] f32.
// Output: patches [4,32,3,128,128] f32 then sampled_attention [4,32] f32, concat flat.
//
// JAX defaults jax_threefry_partitionable=True: bits for element e are
// threefry2x32(key, (hi=0, lo=e)) with the two output words XOR-folded.
//
// SINGLE plain kernel, batch-specialized redundancy (64 blocks/batch).
// Selection via EXACT histogram select (round-12 structure):
//   - fast __logf scores -> monotone u32 keys -> 8192-bin LDS histogram
//   - one-wave suffix scan finds fine bin t* of the 32nd-largest fast key
//   - candidates = all elements in bins >= t*-2 (margin >> fast-vs-exact error)
//   - compacted candidates re-scored (2 waves) with the EXACT ocml logf formula
//     (bit-identical to all prior passing rounds), ranked by
//     (value desc, j asc) == lax.top_k.
// Micro-fixes vs r12: rotated coarse-sum traversal (2-way banks, free) and
// broadcast block-sum (same add order -> bit-identical, one less barrier).

namespace {
constexpr int B      = 4;
constexpr int NP     = 32;     // N_PATCHES
constexpr int PATCH_ = 128;
constexpr int GRID   = 4096;   // 64*64 attention cells per batch
constexpr int HW     = 2048;
constexpr int NT     = 1024;   // threads per block
constexpr int BPB    = 64;     // blocks per batch
constexpr int NBLK   = B * BPB;          // 256 blocks, one per CU
constexpr int NW     = NT / 64;          // 16 waves
constexpr int QP     = GRID / NT;        // 4 scores per thread
constexpr int NBIN   = 8192;   // fine bins: mono >> 19 (order-preserving)
constexpr int NCB    = 128;    // coarse bins: 64 fine each
constexpr int MAXC   = 512;    // candidate capacity (expected ~40-90)
constexpr int GITER  = 6;      // gather float4s per thread
constexpr float EPSF = 1e-12f;

typedef float f32x4 __attribute__((ext_vector_type(4)));

__device__ inline uint32_t rotl32(uint32_t x, uint32_t r){ return (x<<r)|(x>>(32u-r)); }

// Threefry-2x32 with key (0, 42)  == jax.random.key(42)
__device__ inline void threefry2x32_k042(uint32_t x0, uint32_t x1,
                                         uint32_t& o0, uint32_t& o1){
  const uint32_t k0 = 0u, k1 = 42u;
  const uint32_t k2 = k0 ^ k1 ^ 0x1BD11BDAu;
  x0 += k0; x1 += k1;
#define RND(r) { x0 += x1; x1 = rotl32(x1,(r)); x1 ^= x0; }
#define G_A RND(13) RND(15) RND(26) RND(6)
#define G_B RND(17) RND(29) RND(16) RND(24)
  G_A x0 += k1; x1 += k2 + 1u;
  G_B x0 += k2; x1 += k0 + 2u;
  G_A x0 += k0; x1 += k1 + 3u;
  G_B x0 += k1; x1 += k2 + 4u;
  G_A x0 += k2; x1 += k0 + 5u;
#undef G_A
#undef G_B
#undef RND
  o0 = x0; o1 = x1;
}

// Monotone map: u32 compare order == f32 value order.
__device__ inline uint32_t mono_f32(float v){
  const uint32_t bits = __float_as_uint(v);
  return (bits & 0x80000000u) ? ~bits : (bits | 0x80000000u);
}

// uniform bits -> [0,1) float, identical to jax (bits>>9 | one) - 1
__device__ inline float u01(uint32_t bits){
  return __uint_as_float((bits >> 9) | 0x3F800000u) - 1.0f;
}

__global__ __launch_bounds__(NT) void fused_sample_gather(
    const float* __restrict__ att, const float* __restrict__ wsi,
    float* __restrict__ out_attn, f32x4* __restrict__ out4){
  const int tid  = threadIdx.x;
  const int wv   = tid >> 6;        // wave id 0..15
  const int lane = tid & 63;
  const int b    = blockIdx.x >> 6; // this block's batch
  const int g    = blockIdx.x & 63; // slice index within batch
  __shared__ uint32_t hist[NBIN];   // 32 KB, linear layout
  __shared__ uint32_t coarse[NCB];
  __shared__ float redv[NW];
  __shared__ int   scnt;
  __shared__ int   stcut;
  __shared__ unsigned short candj[MAXC];
  __shared__ unsigned long long dkey[MAXC];
  __shared__ float dprob[MAXC];
  __shared__ int2  gtab[NP];        // n -> (y0, x0), this batch only

  const float* a = att + b * GRID;

  // one float4 per thread: j = tid*4 + q (contiguous)
  const float4 va = reinterpret_cast<const float4*>(a)[tid];
  float areg[QP] = {va.x, va.y, va.z, va.w};

  // zero histogram + counter (completes before the barrier below)
  #pragma unroll
  for (int i = 0; i < NBIN / NT; ++i) hist[i * NT + tid] = 0u;
  if (tid == 0) scnt = 0;

  // ---- sum(attention row): wave partials, then every thread accumulates
  //      redv[0..15] in the same order (bit-identical to prior rounds) ----
  float local = areg[0] + areg[1] + areg[2] + areg[3];
  #pragma unroll
  for (int d = 1; d < 64; d <<= 1) local += __shfl_xor(local, d, 64);
  if (lane == 0) redv[wv] = local;
  __syncthreads();                                   // B1
  float sum = 0.f;
  #pragma unroll
  for (int w = 0; w < NW; ++w) sum += redv[w];       // broadcast reads

  // ---- fast scores (filter only) -> monotone keys -> histogram ----
  uint32_t kreg[QP];
  #pragma unroll
  for (int q = 0; q < QP; ++q){
    const int e = b * GRID + (tid << 2) + q;         // flat element in [0, 16384)
    uint32_t o0, o1;
    threefry2x32_k042(0u, (uint32_t)e, o0, o1);
    const float u = u01(o0 ^ o1);
    const float gum = -__logf(-__logf(u + EPSF) + EPSF);   // fast v_log path
    const float s   = __logf(areg[q] / sum + EPSF) + gum;
    kreg[q] = mono_f32(s);
    atomicAdd(&hist[kreg[q] >> 19], 1u);
  }
  __syncthreads();                                   // B2

  // ---- coarse histogram: rotated traversal -> 2-way banks (free, m136) ----
  if (tid < NCB){
    uint32_t s = 0;
    #pragma unroll
    for (int i = 0; i < 64; ++i) s += hist[tid * 64 + ((i + tid) & 63)];
    coarse[tid] = s;
  }
  __syncthreads();                                   // B3

  // ---- one-wave suffix scan: find fine bin t* of the 32nd-largest key ----
  if (wv == 0){
    uint32_t vlo = coarse[lane], vhi = coarse[lane + 64];
    #pragma unroll
    for (int d = 1; d < 64; d <<= 1){
      uint32_t t = __shfl_down(vhi, d, 64); if (lane + d < 64) vhi += t;
      t = __shfl_down(vlo, d, 64);          if (lane + d < 64) vlo += t;
    }
    const uint32_t Thi = __shfl(vhi, 0, 64);   // total of hi half
    const uint32_t Slo = vlo + Thi;            // S(c = lane)
    const unsigned long long mhi = __ballot(vhi >= (uint32_t)NP);
    const unsigned long long mlo = __ballot(Slo >= (uint32_t)NP);
    const int cstar = mhi ? (64 + (63 - __clzll(mhi))) : (63 - __clzll(mlo));
    // A = S(cstar+1): count strictly above coarse bin cstar
    const int cn = cstar + 1;
    const uint32_t t1 = __shfl(vhi, (cn - 64) & 63, 64);
    const uint32_t t2 = __shfl(Slo, cn & 63, 64);
    const uint32_t A  = (cn >= 128) ? 0u : ((cn >= 64) ? t1 : t2);
    // fine suffix within coarse bin cstar (consecutive words, conflict-free)
    uint32_t f = hist[cstar * 64 + lane];
    #pragma unroll
    for (int d = 1; d < 64; d <<= 1){
      uint32_t t = __shfl_down(f, d, 64); if (lane + d < 64) f += t;
    }
    const unsigned long long mf = __ballot(A + f >= (uint32_t)NP);
    const int lstar = 63 - __clzll(mf);        // exists: C(cstar*64) >= 32
    if (lane == 0) stcut = cstar * 64 + lstar - 2;   // 2-bin safety margin
  }
  __syncthreads();                                   // B4
  const int tcut = stcut;

  // ---- append candidates (indices only; rescore stays compacted) ----
  #pragma unroll
  for (int q = 0; q < QP; ++q){
    if ((int)(kreg[q] >> 19) >= tcut){
      const int p = atomicAdd(&scnt, 1);
      if (p < MAXC) candj[p] = (unsigned short)((tid << 2) + q);
    }
  }
  __syncthreads();                                   // B5
  const int M = scnt < MAXC ? scnt : MAXC;

  // ---- exact re-score, 2 waves only (bit-identical ocml logf formula) ----
  if (tid < M){
    const int j = candj[tid];
    const int e = b * GRID + j;
    uint32_t o0, o1;
    threefry2x32_k042(0u, (uint32_t)e, o0, o1);
    const float u = u01(o0 ^ o1);
    const float gum  = -logf(-logf(u + EPSF) + EPSF);
    const float prob = a[j] / sum;
    const float se   = logf(prob + EPSF) + gum;
    dkey[tid]  = ((unsigned long long)mono_f32(se) << 32)
               | (uint32_t)(GRID - 1 - j);
    dprob[tid] = prob;
  }
  __syncthreads();                                   // B6

  // ---- exact rank among M candidates (broadcast reads); rank < 32 -> emit ----
  if (tid < M){
    const unsigned long long mk = dkey[tid];
    int rank = 0;
    #pragma unroll 4
    for (int c = 0; c < M; ++c) rank += (dkey[c] > mk) ? 1 : 0;
    if (rank < NP){
      const int j   = GRID - 1 - (int)(uint32_t)(mk & 0xFFFFFFFFull);
      const int row = j >> 6, col = j & 63;
      int y0 = row * 32 - 48; y0 = y0 < 0 ? 0 : (y0 > 1920 ? 1920 : y0);
      int x0 = col * 32 - 48; x0 = x0 < 0 ? 0 : (x0 > 1920 ? 1920 : x0);
      gtab[rank] = make_int2(y0, x0);
      if (g == 0) out_attn[b * NP + rank] = dprob[tid];
    }
  }
  __syncthreads();                                   // B7

  // ================= gather: this block's 1/64 slice of its batch ============
  // per batch: rows = 32*3*128 = 12288, each row = 32 float4.
  int t = g * NT + tid;                       // [0, 65536) per iteration step
  #pragma unroll
  for (int it = 0; it < GITER; ++it, t += BPB * NT){
    const int l4   = t & 31;          // float4 within the 128-float row
    const int rowb = t >> 5;          // [0, 12288) within batch
    const int r    = rowb & 127;
    const int tmp  = rowb >> 7;       // n*3 + c, [0, 96)
    const int c    = tmp % 3;
    const int n    = tmp / 3;
    const int2 yx  = gtab[n];         // (y0, x0); x0 multiple of 16 -> aligned
    const size_t off = ((size_t)((b * 3 + c) * HW + yx.x + r)) * HW + (size_t)yx.y;
    const f32x4 v = *reinterpret_cast<const f32x4*>(wsi + off + (size_t)l4 * 4);
    __builtin_nontemporal_store(v, out4 + ((size_t)b * 12288 + rowb) * 32 + l4);
  }
}
} // namespace

extern "C" void kernel_launch(void* const* d_in, const int* in_sizes, int n_in,
                              void* d_out, int out_size, void* d_ws, size_t ws_size,
                              hipStream_t stream) {
  const float* att = (const float*)d_in[2];
  const float* wsi = (const float*)d_in[3];
  float* out       = (float*)d_out;
  float* out_attn  = out + (size_t)B * NP * 3 * PATCH_ * PATCH_;  // 6,291,456

  fused_sample_gather<<<NBLK, NT, 0, stream>>>(att, wsi, out_attn, (f32x4*)out);
}